// Round 6
// baseline (236.718 us; speedup 1.0000x reference)
//
#include <hip/hip_runtime.h>

// out = atoms_x - segment_mean(atoms_x, graph_batch)[graph_batch]
// graph_batch SORTED. Fused single pass, ONE WAVE PER BLOCK (no lockstep:
// 16+ independent waves/CU interleave load/compute/store phases freely).
// Per-thread run accumulation (cheap VALU) + tiny per-wave LDS slot table.
// Halo probes are 64-lane ballot-stepped (no serial dependent-load loops).
// Non-temporal output stores keep the 128 MB of inputs L3-resident.

typedef float f32x4 __attribute__((ext_vector_type(4)));  // clang-native for NT store

static constexpr int TPB   = 64;           // one wave
static constexpr int CPT   = 16;           // atoms per thread
static constexpr int CHUNK = TPB * CPT;    // 1024 atoms per block
static constexpr int SLOTS = 128;          // max id-span per chunk (exp ~27)

__global__ __launch_bounds__(TPB) void fused_center_kernel(
    const float* __restrict__ x, const int* __restrict__ gb,
    float* __restrict__ out, int n) {
  __shared__ float sums[SLOTS * 4];  // {sx, sy, sz, cnt} per slot

  const int lane = threadIdx.x;
  const long long cs = (long long)blockIdx.x * CHUNK;
  const long long ce = (cs + CHUNK < (long long)n) ? cs + CHUNK : (long long)n;
  const int fid = gb[cs];
  const int lid = gb[ce - 1];
  const int span = lid - fid + 1;

  if (span > SLOTS) {
    // Pathological id-sparsity; block-uniform branch, never hot, correct.
    if (lane == 0) {
      long long i = cs;
      while (i < ce) {
        int id = gb[i];
        long long rs = i; while (rs > 0 && gb[rs - 1] == id) --rs;
        long long re = i; while (re < n && gb[re] == id) ++re;
        float sx = 0.f, sy = 0.f, sz = 0.f;
        for (long long k = rs; k < re; ++k) {
          sx += x[k * 3 + 0]; sy += x[k * 3 + 1]; sz += x[k * 3 + 2];
        }
        float inv = 1.f / (float)(re - rs);
        float mx = sx * inv, my = sy * inv, mz = sz * inv;
        long long we = (re < ce) ? re : ce;
        for (long long k = i; k < we; ++k) {
          out[k * 3 + 0] = x[k * 3 + 0] - mx;
          out[k * 3 + 1] = x[k * 3 + 1] - my;
          out[k * 3 + 2] = x[k * 3 + 2] - mz;
        }
        i = we;
      }
    }
    return;
  }

  const long long base = cs + (long long)lane * CPT;
  const bool full = (base + CPT <= ce);

  // ---- issue all global loads first (hide latency under LDS init) ----
  float f[CPT * 3];
  int ids[CPT];
  if (full) {
    const float4* xv = reinterpret_cast<const float4*>(x + base * 3);
#pragma unroll
    for (int j = 0; j < CPT * 3 / 4; ++j) {
      float4 v = xv[j];
      f[j * 4 + 0] = v.x; f[j * 4 + 1] = v.y;
      f[j * 4 + 2] = v.z; f[j * 4 + 3] = v.w;
    }
    const int4* gv = reinterpret_cast<const int4*>(gb + base);
#pragma unroll
    for (int j = 0; j < CPT / 4; ++j) {
      int4 g = gv[j];
      ids[j * 4 + 0] = g.x; ids[j * 4 + 1] = g.y;
      ids[j * 4 + 2] = g.z; ids[j * 4 + 3] = g.w;
    }
  }

  // zero the slot table (span*4 <= 512 words; 64 lanes)
  for (int i = lane; i < span * 4; i += TPB) sums[i] = 0.f;
  __syncthreads();  // single wave: ~free (lgkmcnt drain + trivial barrier)

  if (full) {
    // ---- per-thread run accumulation, flush at id boundaries ----
    int cur = ids[0];
    float sx = 0.f, sy = 0.f, sz = 0.f, sc = 0.f;
#pragma unroll
    for (int j = 0; j < CPT; ++j) {
      if (ids[j] != cur) {
        int s = (cur - fid) * 4;
        atomicAdd(&sums[s + 0], sx); atomicAdd(&sums[s + 1], sy);
        atomicAdd(&sums[s + 2], sz); atomicAdd(&sums[s + 3], sc);
        cur = ids[j]; sx = sy = sz = sc = 0.f;
      }
      sx += f[j * 3 + 0]; sy += f[j * 3 + 1]; sz += f[j * 3 + 2]; sc += 1.f;
    }
    {
      int s = (cur - fid) * 4;
      atomicAdd(&sums[s + 0], sx); atomicAdd(&sums[s + 1], sy);
      atomicAdd(&sums[s + 2], sz); atomicAdd(&sums[s + 3], sc);
    }
  } else if (base < ce) {
    for (long long i = base; i < ce; ++i) {
      int s = (gb[i] - fid) * 4;
      atomicAdd(&sums[s + 0], x[i * 3 + 0]);
      atomicAdd(&sums[s + 1], x[i * 3 + 1]);
      atomicAdd(&sums[s + 2], x[i * 3 + 2]);
      atomicAdd(&sums[s + 3], 1.f);
    }
  }

  // ---- halos: 64-lane ballot-stepped probes (no serial dependent loops) ----
  if (cs > 0) {
    float hx = 0.f, hy = 0.f, hz = 0.f, hc = 0.f;
    long long off = 1 + lane;  // distance back from cs
    for (;;) {
      long long i = cs - off;
      bool m = (i >= 0) && (gb[i] == fid);
      if (m) {
        hx += x[i * 3 + 0]; hy += x[i * 3 + 1]; hz += x[i * 3 + 2]; hc += 1.f;
      }
      if (__popcll(__ballot(m)) < TPB) break;  // run ended within this window
      off += TPB;
    }
#pragma unroll
    for (int d = 1; d < 64; d <<= 1) {
      hx += __shfl_xor(hx, d); hy += __shfl_xor(hy, d);
      hz += __shfl_xor(hz, d); hc += __shfl_xor(hc, d);
    }
    if (lane == 0 && hc > 0.f) {
      atomicAdd(&sums[0], hx); atomicAdd(&sums[1], hy);
      atomicAdd(&sums[2], hz); atomicAdd(&sums[3], hc);
    }
  }
  if (ce < (long long)n) {
    float hx = 0.f, hy = 0.f, hz = 0.f, hc = 0.f;
    long long off = (long long)lane;
    for (;;) {
      long long i = ce + off;
      bool m = (i < (long long)n) && (gb[i] == lid);
      if (m) {
        hx += x[i * 3 + 0]; hy += x[i * 3 + 1]; hz += x[i * 3 + 2]; hc += 1.f;
      }
      if (__popcll(__ballot(m)) < TPB) break;
      off += TPB;
    }
#pragma unroll
    for (int d = 1; d < 64; d <<= 1) {
      hx += __shfl_xor(hx, d); hy += __shfl_xor(hy, d);
      hz += __shfl_xor(hz, d); hc += __shfl_xor(hc, d);
    }
    if (lane == 0 && hc > 0.f) {
      int s = (lid - fid) * 4;
      atomicAdd(&sums[s + 0], hx); atomicAdd(&sums[s + 1], hy);
      atomicAdd(&sums[s + 2], hz); atomicAdd(&sums[s + 3], hc);
    }
  }
  __syncthreads();

  // ---- sums -> means (in LDS) ----
  for (int s = lane; s < span; s += TPB) {
    float c = sums[s * 4 + 3];
    if (c > 0.f) {
      float inv = 1.f / c;
      sums[s * 4 + 0] *= inv; sums[s * 4 + 1] *= inv; sums[s * 4 + 2] *= inv;
    }
  }
  __syncthreads();

  // ---- subtract in place + non-temporal store ----
  if (full) {
#pragma unroll
    for (int j = 0; j < CPT; ++j) {
      int s = (ids[j] - fid) * 4;
      f[j * 3 + 0] -= sums[s + 0];
      f[j * 3 + 1] -= sums[s + 1];
      f[j * 3 + 2] -= sums[s + 2];
    }
    f32x4* ov = reinterpret_cast<f32x4*>(out + base * 3);
#pragma unroll
    for (int j = 0; j < CPT * 3 / 4; ++j) {
      f32x4 o = {f[j * 4 + 0], f[j * 4 + 1], f[j * 4 + 2], f[j * 4 + 3]};
      __builtin_nontemporal_store(o, &ov[j]);
    }
  } else if (base < ce) {
    for (long long i = base; i < ce; ++i) {
      int s = (gb[i] - fid) * 4;
      out[i * 3 + 0] = x[i * 3 + 0] - sums[s + 0];
      out[i * 3 + 1] = x[i * 3 + 1] - sums[s + 1];
      out[i * 3 + 2] = x[i * 3 + 2] - sums[s + 2];
    }
  }
}

extern "C" void kernel_launch(void* const* d_in, const int* in_sizes, int n_in,
                              void* d_out, int out_size, void* d_ws, size_t ws_size,
                              hipStream_t stream) {
  const float* x = (const float*)d_in[0];
  const int* gb = (const int*)d_in[1];
  float* out = (float*)d_out;
  const int n = in_sizes[0] / 3;  // atoms

  int blocks = (int)(((long long)n + CHUNK - 1) / CHUNK);
  fused_center_kernel<<<blocks, TPB, 0, stream>>>(x, gb, out, n);
}

// Round 7
// 54.396 us; speedup vs baseline: 4.3517x; 4.3517x over previous
//
#include <hip/hip_runtime.h>

// out = atoms_x - segment_mean(atoms_x, graph_batch)[graph_batch]
// graph_batch SORTED. Fused single pass, ONE WAVE PER BLOCK (no cross-wave
// barriers; ~16 independent blocks/CU interleave phases freely).
// Per-thread run accumulation + per-wave LDS slot table; ballot-stepped
// parallel halo probes. REGULAR float4 stores (NT stores caused 3x write
// amplification in round 6: 64B lines assembled in L2, never bypass it).

static constexpr int TPB   = 64;           // one wave
static constexpr int CPT   = 16;           // atoms per thread
static constexpr int CHUNK = TPB * CPT;    // 1024 atoms per block
static constexpr int SLOTS = 128;          // max id-span per chunk (exp ~27)

__global__ __launch_bounds__(TPB) void fused_center_kernel(
    const float* __restrict__ x, const int* __restrict__ gb,
    float* __restrict__ out, int n) {
  __shared__ float sums[SLOTS * 4];  // {sx, sy, sz, cnt} per slot

  const int lane = threadIdx.x;
  const long long cs = (long long)blockIdx.x * CHUNK;
  const long long ce = (cs + CHUNK < (long long)n) ? cs + CHUNK : (long long)n;
  const int fid = gb[cs];
  const int lid = gb[ce - 1];
  const int span = lid - fid + 1;

  if (span > SLOTS) {
    // Pathological id-sparsity; block-uniform branch, never hot, correct.
    if (lane == 0) {
      long long i = cs;
      while (i < ce) {
        int id = gb[i];
        long long rs = i; while (rs > 0 && gb[rs - 1] == id) --rs;
        long long re = i; while (re < n && gb[re] == id) ++re;
        float sx = 0.f, sy = 0.f, sz = 0.f;
        for (long long k = rs; k < re; ++k) {
          sx += x[k * 3 + 0]; sy += x[k * 3 + 1]; sz += x[k * 3 + 2];
        }
        float inv = 1.f / (float)(re - rs);
        float mx = sx * inv, my = sy * inv, mz = sz * inv;
        long long we = (re < ce) ? re : ce;
        for (long long k = i; k < we; ++k) {
          out[k * 3 + 0] = x[k * 3 + 0] - mx;
          out[k * 3 + 1] = x[k * 3 + 1] - my;
          out[k * 3 + 2] = x[k * 3 + 2] - mz;
        }
        i = we;
      }
    }
    return;
  }

  const long long base = cs + (long long)lane * CPT;
  const bool full = (base + CPT <= ce);

  // ---- issue all global loads first (hide latency under LDS init) ----
  float f[CPT * 3];
  int ids[CPT];
  if (full) {
    const float4* xv = reinterpret_cast<const float4*>(x + base * 3);
#pragma unroll
    for (int j = 0; j < CPT * 3 / 4; ++j) {
      float4 v = xv[j];
      f[j * 4 + 0] = v.x; f[j * 4 + 1] = v.y;
      f[j * 4 + 2] = v.z; f[j * 4 + 3] = v.w;
    }
    const int4* gv = reinterpret_cast<const int4*>(gb + base);
#pragma unroll
    for (int j = 0; j < CPT / 4; ++j) {
      int4 g = gv[j];
      ids[j * 4 + 0] = g.x; ids[j * 4 + 1] = g.y;
      ids[j * 4 + 2] = g.z; ids[j * 4 + 3] = g.w;
    }
  }

  // zero the slot table (span*4 <= 512 words; 64 lanes)
  for (int i = lane; i < span * 4; i += TPB) sums[i] = 0.f;
  __syncthreads();  // single wave: cheap

  if (full) {
    // ---- per-thread run accumulation, flush at id boundaries ----
    int cur = ids[0];
    float sx = 0.f, sy = 0.f, sz = 0.f, sc = 0.f;
#pragma unroll
    for (int j = 0; j < CPT; ++j) {
      if (ids[j] != cur) {
        int s = (cur - fid) * 4;
        atomicAdd(&sums[s + 0], sx); atomicAdd(&sums[s + 1], sy);
        atomicAdd(&sums[s + 2], sz); atomicAdd(&sums[s + 3], sc);
        cur = ids[j]; sx = sy = sz = sc = 0.f;
      }
      sx += f[j * 3 + 0]; sy += f[j * 3 + 1]; sz += f[j * 3 + 2]; sc += 1.f;
    }
    {
      int s = (cur - fid) * 4;
      atomicAdd(&sums[s + 0], sx); atomicAdd(&sums[s + 1], sy);
      atomicAdd(&sums[s + 2], sz); atomicAdd(&sums[s + 3], sc);
    }
  } else if (base < ce) {
    for (long long i = base; i < ce; ++i) {
      int s = (gb[i] - fid) * 4;
      atomicAdd(&sums[s + 0], x[i * 3 + 0]);
      atomicAdd(&sums[s + 1], x[i * 3 + 1]);
      atomicAdd(&sums[s + 2], x[i * 3 + 2]);
      atomicAdd(&sums[s + 3], 1.f);
    }
  }

  // ---- halos: 64-lane ballot-stepped probes (no serial dependent loops) ----
  if (cs > 0) {
    float hx = 0.f, hy = 0.f, hz = 0.f, hc = 0.f;
    long long off = 1 + lane;  // distance back from cs
    for (;;) {
      long long i = cs - off;
      bool m = (i >= 0) && (gb[i] == fid);
      if (m) {
        hx += x[i * 3 + 0]; hy += x[i * 3 + 1]; hz += x[i * 3 + 2]; hc += 1.f;
      }
      if (__popcll(__ballot(m)) < TPB) break;  // run ended within this window
      off += TPB;
    }
#pragma unroll
    for (int d = 1; d < 64; d <<= 1) {
      hx += __shfl_xor(hx, d); hy += __shfl_xor(hy, d);
      hz += __shfl_xor(hz, d); hc += __shfl_xor(hc, d);
    }
    if (lane == 0 && hc > 0.f) {
      atomicAdd(&sums[0], hx); atomicAdd(&sums[1], hy);
      atomicAdd(&sums[2], hz); atomicAdd(&sums[3], hc);
    }
  }
  if (ce < (long long)n) {
    float hx = 0.f, hy = 0.f, hz = 0.f, hc = 0.f;
    long long off = (long long)lane;
    for (;;) {
      long long i = ce + off;
      bool m = (i < (long long)n) && (gb[i] == lid);
      if (m) {
        hx += x[i * 3 + 0]; hy += x[i * 3 + 1]; hz += x[i * 3 + 2]; hc += 1.f;
      }
      if (__popcll(__ballot(m)) < TPB) break;
      off += TPB;
    }
#pragma unroll
    for (int d = 1; d < 64; d <<= 1) {
      hx += __shfl_xor(hx, d); hy += __shfl_xor(hy, d);
      hz += __shfl_xor(hz, d); hc += __shfl_xor(hc, d);
    }
    if (lane == 0 && hc > 0.f) {
      int s = (lid - fid) * 4;
      atomicAdd(&sums[s + 0], hx); atomicAdd(&sums[s + 1], hy);
      atomicAdd(&sums[s + 2], hz); atomicAdd(&sums[s + 3], hc);
    }
  }
  __syncthreads();

  // ---- sums -> means (in LDS) ----
  for (int s = lane; s < span; s += TPB) {
    float c = sums[s * 4 + 3];
    if (c > 0.f) {
      float inv = 1.f / c;
      sums[s * 4 + 0] *= inv; sums[s * 4 + 1] *= inv; sums[s * 4 + 2] *= inv;
    }
  }
  __syncthreads();

  // ---- subtract + regular float4 stores (L2 assembles full lines) ----
  if (full) {
#pragma unroll
    for (int j = 0; j < CPT; ++j) {
      int s = (ids[j] - fid) * 4;
      f[j * 3 + 0] -= sums[s + 0];
      f[j * 3 + 1] -= sums[s + 1];
      f[j * 3 + 2] -= sums[s + 2];
    }
    float4* ov = reinterpret_cast<float4*>(out + base * 3);
#pragma unroll
    for (int j = 0; j < CPT * 3 / 4; ++j)
      ov[j] = make_float4(f[j * 4 + 0], f[j * 4 + 1],
                          f[j * 4 + 2], f[j * 4 + 3]);
  } else if (base < ce) {
    for (long long i = base; i < ce; ++i) {
      int s = (gb[i] - fid) * 4;
      out[i * 3 + 0] = x[i * 3 + 0] - sums[s + 0];
      out[i * 3 + 1] = x[i * 3 + 1] - sums[s + 1];
      out[i * 3 + 2] = x[i * 3 + 2] - sums[s + 2];
    }
  }
}

extern "C" void kernel_launch(void* const* d_in, const int* in_sizes, int n_in,
                              void* d_out, int out_size, void* d_ws, size_t ws_size,
                              hipStream_t stream) {
  const float* x = (const float*)d_in[0];
  const int* gb = (const int*)d_in[1];
  float* out = (float*)d_out;
  const int n = in_sizes[0] / 3;  // atoms

  int blocks = (int)(((long long)n + CHUNK - 1) / CHUNK);
  fused_center_kernel<<<blocks, TPB, 0, stream>>>(x, gb, out, n);
}